// Round 2
// baseline (1614.939 us; speedup 1.0000x reference)
//
#include <hip/hip_runtime.h>

#define NUM_E   16384
#define DIM     256
#define NROWS   8192      // B*H*W
#define HW      1024      // H*W
#define NSPL    32        // n-splits: each k_score block covers 512 cols
#define BM      128
#define BN      128
#define NT      4         // n-tiles of 128 per block
#define BK      64

typedef __bf16 bf16x8 __attribute__((ext_vector_type(8)));
typedef float  f32x4  __attribute__((ext_vector_type(4)));

__device__ __forceinline__ unsigned short f2bf(float x) {
    unsigned u = __float_as_uint(x);
    unsigned r = (u + 0x7fffu + ((u >> 16) & 1u)) >> 16;
    return (unsigned short)r;
}
__device__ __forceinline__ float bf2f(unsigned short h) {
    return __uint_as_float(((unsigned)h) << 16);
}
__device__ __forceinline__ void async_copy16(const void* g, void* l) {
    __builtin_amdgcn_global_load_lds(
        (const __attribute__((address_space(1))) unsigned int*)g,
        (__attribute__((address_space(3))) unsigned int*)l, 16, 0, 0);
}
__device__ __forceinline__ void top2_merge(float& V1, int& I1, float& V2, int& I2,
                                           float w, int j) {
    if (w > V1 || (w == V1 && j < I1)) { V2 = V1; I2 = I1; V1 = w; I1 = j; }
    else if (w > V2 || (w == V2 && j < I2)) { V2 = w; I2 = j; }
}

// ---------------- inverse norms ----------------
__global__ void k_inv_e(const float* __restrict__ emb, float* __restrict__ inv_e) {
    int w = threadIdx.x >> 6, lane = threadIdx.x & 63;
    int k = blockIdx.x * 4 + w;
    float4 v = *(const float4*)(emb + (size_t)k * DIM + lane * 4);
    float s = v.x*v.x + v.y*v.y + v.z*v.z + v.w*v.w;
    for (int off = 32; off > 0; off >>= 1) s += __shfl_down(s, off);
    if (lane == 0) inv_e[k] = 1.0f / fmaxf(sqrtf(s), 1e-12f);
}

__global__ void k_inv_z(const float* __restrict__ z, float* __restrict__ inv_z) {
    int n = blockIdx.x * 256 + threadIdx.x;
    int b = n >> 10, hw = n & 1023;
    const float* p = z + (size_t)b * DIM * HW + hw;
    float s = 0.f;
    #pragma unroll 8
    for (int c = 0; c < DIM; c++) { float v = p[c * HW]; s += v * v; }
    inv_z[n] = 1.0f / fmaxf(sqrtf(s), 1e-12f);
}

// ---------------- prep: normalized bf16 hi/lo splits ----------------
// Zh/Zl: [8192][256] row-major (transpose from [B,C,HW])
__global__ void k_prep_z(const float* __restrict__ z, const float* __restrict__ inv_z,
                         unsigned short* __restrict__ Zh, unsigned short* __restrict__ Zl) {
    __shared__ float T[64 * 68];
    int t = threadIdx.x;
    int n0 = blockIdx.x * 64, c0 = blockIdx.y * 64;
    int b = n0 >> 10, hw0 = n0 & 1023;
    #pragma unroll
    for (int i = 0; i < 4; i++) {
        int f = t + 256 * i;
        int cc = f >> 4, n4 = (f & 15) * 4;
        float4 v  = *(const float4*)(z + (size_t)(b * DIM + c0 + cc) * HW + hw0 + n4);
        float4 iv = *(const float4*)(inv_z + n0 + n4);
        v.x *= iv.x; v.y *= iv.y; v.z *= iv.z; v.w *= iv.w;
        *(float4*)&T[cc * 68 + n4] = v;
    }
    __syncthreads();
    #pragma unroll
    for (int i = 0; i < 4; i++) {
        int f = t + 256 * i;
        int nn = f >> 4, c4 = (f & 15) * 4;
        ushort4 h, lo;
        float x;
        x = T[(c4+0)*68 + nn]; h.x = f2bf(x); lo.x = f2bf(x - bf2f(h.x));
        x = T[(c4+1)*68 + nn]; h.y = f2bf(x); lo.y = f2bf(x - bf2f(h.y));
        x = T[(c4+2)*68 + nn]; h.z = f2bf(x); lo.z = f2bf(x - bf2f(h.z));
        x = T[(c4+3)*68 + nn]; h.w = f2bf(x); lo.w = f2bf(x - bf2f(h.w));
        size_t o = (size_t)(n0 + nn) * DIM + c0 + c4;
        *(ushort4*)(Zh + o) = h;
        *(ushort4*)(Zl + o) = lo;
    }
}

// Eh/El: [16384][256] row-major
__global__ void k_prep_e(const float* __restrict__ emb, const float* __restrict__ inv_e,
                         unsigned short* __restrict__ Eh, unsigned short* __restrict__ El) {
    int g = blockIdx.x * 256 + threadIdx.x;     // float4 id, < 1048576
    float4 v = *(const float4*)(emb + (size_t)g * 4);
    float s = inv_e[g >> 6];
    v.x *= s; v.y *= s; v.z *= s; v.w *= s;
    ushort4 h, lo;
    h.x = f2bf(v.x); lo.x = f2bf(v.x - bf2f(h.x));
    h.y = f2bf(v.y); lo.y = f2bf(v.y - bf2f(h.y));
    h.z = f2bf(v.z); lo.z = f2bf(v.z - bf2f(h.z));
    h.w = f2bf(v.w); lo.w = f2bf(v.w - bf2f(h.w));
    *(ushort4*)(Eh + (size_t)g * 4) = h;
    *(ushort4*)(El + (size_t)g * 4) = lo;
}

// ---------------- MFMA bf16x2 score + per-row top-2 ----------------
__launch_bounds__(256, 2)
__global__ void k_score(const unsigned short* __restrict__ Zh, const unsigned short* __restrict__ Zl,
                        const unsigned short* __restrict__ Eh, const unsigned short* __restrict__ El,
                        f32x4* __restrict__ part) {
    __shared__ __align__(16) unsigned short lds[32768];  // Ah|Al|Bh|Bl, 8192 each
    const int t = threadIdx.x, l = t & 63, w = t >> 6;
    const int wm = w >> 1, wn = w & 1;
    const int m0 = blockIdx.y * BM;
    const int n0 = blockIdx.x * (BN * NT);
    const int lm = l & 15, kh = l >> 4;

    float rv1 = -2e9f, rv2 = -2e9f; int ri1 = 0, ri2 = 0;   // row m0+t (t<128)

    for (int nt = 0; nt < NT; nt++) {
        const int nb = n0 + nt * BN;
        f32x4 acc[4][4];
        #pragma unroll
        for (int i = 0; i < 4; i++)
            #pragma unroll
            for (int j = 0; j < 4; j++) acc[i][j] = (f32x4)0.f;

        for (int kc = 0; kc < DIM; kc += BK) {
            #pragma unroll
            for (int q = 0; q < 4; q++) {
                int it = w * 4 + q;                 // 0..15
                int r = it * 8 + (l >> 3);
                int go = kc + (l & 7) * 8;
                async_copy16(Zh + (size_t)(m0 + r) * DIM + go, &lds[        it * 512]);
                async_copy16(Zl + (size_t)(m0 + r) * DIM + go, &lds[ 8192 + it * 512]);
                async_copy16(Eh + (size_t)(nb + r) * DIM + go, &lds[16384 + it * 512]);
                async_copy16(El + (size_t)(nb + r) * DIM + go, &lds[24576 + it * 512]);
            }
            __syncthreads();
            #pragma unroll
            for (int ks = 0; ks < BK; ks += 32) {
                bf16x8 ah[4], al[4], bh[4], bl[4];
                #pragma unroll
                for (int i = 0; i < 4; i++) {
                    int ra = (wm * 64 + i * 16 + lm) * BK + ks + kh * 8;
                    int rb = (wn * 64 + i * 16 + lm) * BK + ks + kh * 8;
                    ah[i] = *(const bf16x8*)&lds[        ra];
                    al[i] = *(const bf16x8*)&lds[ 8192 + ra];
                    bh[i] = *(const bf16x8*)&lds[16384 + rb];
                    bl[i] = *(const bf16x8*)&lds[24576 + rb];
                }
                #pragma unroll
                for (int i = 0; i < 4; i++)
                    #pragma unroll
                    for (int j = 0; j < 4; j++) {
                        acc[i][j] = __builtin_amdgcn_mfma_f32_16x16x32_bf16(ah[i], bh[j], acc[i][j], 0, 0, 0);
                        acc[i][j] = __builtin_amdgcn_mfma_f32_16x16x32_bf16(ah[i], bl[j], acc[i][j], 0, 0, 0);
                        acc[i][j] = __builtin_amdgcn_mfma_f32_16x16x32_bf16(al[i], bh[j], acc[i][j], 0, 0, 0);
                    }
            }
            __syncthreads();
        }
        // epilogue: per-row top-2 over this nt's 128 cols
        f32x4* red = (f32x4*)lds;                   // [128][2]
        #pragma unroll
        for (int i = 0; i < 4; i++) {
            #pragma unroll
            for (int reg = 0; reg < 4; reg++) {
                float V1 = -2e9f, V2 = -2e9f; int I1 = 0, I2 = 0;
                #pragma unroll
                for (int j = 0; j < 4; j++) {
                    float v = acc[i][j][reg];
                    int c = nb + wn * 64 + j * 16 + lm;
                    top2_merge(V1, I1, V2, I2, v, c);
                }
                #pragma unroll
                for (int m = 1; m <= 8; m <<= 1) {
                    float w1 = __shfl_xor(V1, m); int j1 = __shfl_xor(I1, m);
                    float w2 = __shfl_xor(V2, m); int j2 = __shfl_xor(I2, m);
                    top2_merge(V1, I1, V2, I2, w1, j1);
                    top2_merge(V1, I1, V2, I2, w2, j2);
                }
                if (lm == 0) {
                    int row = wm * 64 + i * 16 + kh * 4 + reg;
                    f32x4 e; e[0] = V1; e[1] = __int_as_float(I1);
                    e[2] = V2; e[3] = __int_as_float(I2);
                    red[row * 2 + wn] = e;
                }
            }
        }
        __syncthreads();
        if (t < BM) {
            #pragma unroll
            for (int s = 0; s < 2; s++) {
                f32x4 e = red[t * 2 + s];
                top2_merge(rv1, ri1, rv2, ri2, e[0], __float_as_int(e[1]));
                top2_merge(rv1, ri1, rv2, ri2, e[2], __float_as_int(e[3]));
            }
        }
        __syncthreads();
    }
    if (t < BM) {
        f32x4 e; e[0] = rv1; e[1] = __int_as_float(ri1);
        e[2] = rv2; e[3] = __int_as_float(ri2);
        part[(size_t)blockIdx.x * NROWS + m0 + t] = e;
    }
}

// ---------------- cross-split reduce + fp64 rescore of near-ties ----------------
__global__ void k_final(const f32x4* __restrict__ part, const float* __restrict__ z,
                        const float* __restrict__ emb, int* __restrict__ idx_ws,
                        float* __restrict__ out_idx) {
    int n = blockIdx.x * 256 + threadIdx.x;
    float V1 = -2e9f, V2 = -2e9f; int I1 = 0, I2 = 0;
    for (int s = 0; s < NSPL; s++) {
        f32x4 e = part[(size_t)s * NROWS + n];
        float cv1 = e[0]; int ci1 = __float_as_int(e[1]);
        float cv2 = e[2]; int ci2 = __float_as_int(e[3]);
        if (cv1 > V1 || (cv1 == V1 && ci1 < I1)) { V2 = V1; I2 = I1; V1 = cv1; I1 = ci1; }
        else if (cv1 > V2 || (cv1 == V2 && ci1 < I2)) { V2 = cv1; I2 = ci1; }
        if (cv2 > V2 || (cv2 == V2 && ci2 < I2)) { V2 = cv2; I2 = ci2; }
    }
    int best = I1;
    if (V1 - V2 < 1e-4f) {
        int b = n >> 10, hw = n & 1023;
        const float* zp = z + (size_t)b * DIM * HW + hw;
        const float* e1 = emb + (size_t)I1 * DIM;
        const float* e2 = emb + (size_t)I2 * DIM;
        double sz = 0, d1 = 0, d2 = 0, s1e = 0, s2e = 0;
        for (int c = 0; c < DIM; c++) {
            double zv = (double)zp[c * HW];
            double a1 = (double)e1[c], a2 = (double)e2[c];
            sz += zv * zv; d1 += zv * a1; d2 += zv * a2;
            s1e += a1 * a1; s2e += a2 * a2;
        }
        double q1 = d1 / (sqrt(sz) * sqrt(s1e));
        double q2 = d2 / (sqrt(sz) * sqrt(s2e));
        best = (q2 > q1 || (q2 == q1 && I2 < I1)) ? I2 : I1;
    }
    idx_ws[n] = best;
    out_idx[n] = (float)best;
}

// ---------------- gather z_q from bf16 hi/lo (coalesced writes) ----------------
__global__ void k_zq(const int* __restrict__ idx_ws, const unsigned short* __restrict__ Eh,
                     const unsigned short* __restrict__ El, float* __restrict__ zq) {
    int t = threadIdx.x;
    int n = blockIdx.x * 256 + t;
    int b = n >> 10, hw = n & 1023;
    int id = idx_ws[n];
    const unsigned short* rh = Eh + (size_t)id * DIM;
    const unsigned short* rl = El + (size_t)id * DIM;
    for (int c0 = 0; c0 < DIM; c0 += 8) {
        uint4 hh = *(const uint4*)(rh + c0);
        uint4 ll = *(const uint4*)(rl + c0);
        float v[8];
        v[0] = bf2f(hh.x & 0xffff) + bf2f(ll.x & 0xffff);
        v[1] = bf2f(hh.x >> 16)    + bf2f(ll.x >> 16);
        v[2] = bf2f(hh.y & 0xffff) + bf2f(ll.y & 0xffff);
        v[3] = bf2f(hh.y >> 16)    + bf2f(ll.y >> 16);
        v[4] = bf2f(hh.z & 0xffff) + bf2f(ll.z & 0xffff);
        v[5] = bf2f(hh.z >> 16)    + bf2f(ll.z >> 16);
        v[6] = bf2f(hh.w & 0xffff) + bf2f(ll.w & 0xffff);
        v[7] = bf2f(hh.w >> 16)    + bf2f(ll.w >> 16);
        #pragma unroll
        for (int j = 0; j < 8; j++)
            zq[(size_t)(b * DIM + c0 + j) * HW + hw] = v[j];
    }
}

extern "C" void kernel_launch(void* const* d_in, const int* in_sizes, int n_in,
                              void* d_out, int out_size, void* d_ws, size_t ws_size,
                              hipStream_t stream) {
    const float* z   = (const float*)d_in[0];
    const float* emb = (const float*)d_in[1];

    unsigned short* Zh = (unsigned short*)d_ws;           // 2,097,152 u16
    unsigned short* Zl = Zh + (size_t)NROWS * DIM;
    unsigned short* Eh = Zl + (size_t)NROWS * DIM;        // 4,194,304 u16
    unsigned short* El = Eh + (size_t)NUM_E * DIM;
    float* inv_e = (float*)(El + (size_t)NUM_E * DIM);
    float* inv_z = inv_e + NUM_E;
    f32x4* part  = (f32x4*)(inv_z + NROWS);               // 32*8192 entries
    int* idx_ws  = (int*)((float*)part + (size_t)NSPL * NROWS * 4);

    float* zq      = (float*)d_out;
    float* out_idx = zq + (size_t)NROWS * DIM;

    k_inv_e  <<<NUM_E / 4, 256, 0, stream>>>(emb, inv_e);
    k_inv_z  <<<NROWS / 256, 256, 0, stream>>>(z, inv_z);
    k_prep_z <<<dim3(NROWS / 64, DIM / 64), 256, 0, stream>>>(z, inv_z, Zh, Zl);
    k_prep_e <<<NUM_E * DIM / 1024, 256, 0, stream>>>(emb, inv_e, Eh, El);
    k_score  <<<dim3(NSPL, NROWS / BM), 256, 0, stream>>>(Zh, Zl, Eh, El, part);
    k_final  <<<NROWS / 256, 256, 0, stream>>>(part, z, emb, idx_ws, out_idx);
    k_zq     <<<NROWS / 256, 256, 0, stream>>>(idx_ws, Eh, El, zq);
}